// Round 2
// baseline (406.014 us; speedup 1.0000x reference)
//
#include <hip/hip_runtime.h>

// AttentionWindow (BEiT windowed attention), MI355X gfx950.
// B=64 N=197 DIM=768 H=12 hd=64. bf16 MFMA (16x16x32) for all GEMMs, fp32 softmax.
// R2 fix: LDS tile geometry in k_qkv/k_proj was inconsistent (staged K=32,
// read K=64 -> read unwritten LDS garbage -> NaN). Now BK=64, stride 72.

#define B_    64
#define N_    197
#define DIM_  768
#define H_    12
#define HD_   64
#define M_TOT (B_ * N_)     // 12608
#define LSTR  72            // LDS row stride (shorts): 144B = 36 banks, 16B-aligned

typedef __attribute__((ext_vector_type(8))) short bf8;
typedef __attribute__((ext_vector_type(4))) float f4;

__device__ __forceinline__ unsigned short f2bf(float f) {
    unsigned u = __float_as_uint(f);
    u = (u + 0x7fffu + ((u >> 16) & 1u)) >> 16;
    return (unsigned short)u;
}

// ---------------- prep: fp32->bf16 converts, bias gather, vT pad zero ----------------
__global__ void k_prep(const float* __restrict__ x, const float* __restrict__ qkvw,
                       const float* __restrict__ projw, const float* __restrict__ rpb,
                       const int* __restrict__ relidx,
                       unsigned short* __restrict__ x_bf, unsigned short* __restrict__ qkvw_bf,
                       unsigned short* __restrict__ projw_bf, float* __restrict__ bias_hqk,
                       unsigned short* __restrict__ v_ws) {
    const int T = gridDim.x * blockDim.x;
    const int tid = blockIdx.x * blockDim.x + threadIdx.x;
    for (int i = tid; i < M_TOT * DIM_; i += T) x_bf[i] = f2bf(x[i]);
    for (int i = tid; i < 3 * DIM_ * DIM_; i += T) qkvw_bf[i] = f2bf(qkvw[i]);
    for (int i = tid; i < DIM_ * DIM_; i += T) projw_bf[i] = f2bf(projw[i]);
    for (int i = tid; i < H_ * N_ * N_; i += T) {
        int h = i / (N_ * N_), qk = i - h * (N_ * N_);
        bias_hqk[i] = rpb[relidx[qk] * H_ + h];
    }
    // zero vT columns 197..223 (PV K-padding)
    for (int i = tid; i < B_ * H_ * HD_ * 27; i += T) {
        int row = i / 27, c = 197 + (i - row * 27);
        v_ws[row * 224 + c] = 0;
    }
}

// ---------------- QKV GEMM: (12608x768) @ (2304x768)^T, scatter epilogue ----------------
__global__ __launch_bounds__(256) void k_qkv(const unsigned short* __restrict__ A,
                                             const unsigned short* __restrict__ Bm,
                                             const float* __restrict__ qb, const float* __restrict__ vbias,
                                             unsigned short* __restrict__ q_ws,
                                             unsigned short* __restrict__ k_ws,
                                             unsigned short* __restrict__ v_ws) {
    __shared__ unsigned short a_sh[128 * LSTR];
    __shared__ unsigned short b_sh[128 * LSTR];
    const int t = threadIdx.x;
    const int w = t >> 6, lane = t & 63, ln = lane & 15, quad = lane >> 4;
    const int wm = w & 1, wn = w >> 1;
    const int bm = blockIdx.x, bn = blockIdx.y;

    f4 acc[4][4] = {};

    for (int kt = 0; kt < 12; ++kt) {           // BK = 64
        __syncthreads();
#pragma unroll
        for (int it = 0; it < 4; ++it) {
            int s = t + it * 256;               // 0..1023
            int row = s >> 3, sg = s & 7;       // row 0..127, col = sg*8 (0..63)
            int gr = bm * 128 + row;
            uint4 va = make_uint4(0, 0, 0, 0);
            if (gr < M_TOT) va = *(const uint4*)(A + gr * 768 + kt * 64 + sg * 8);
            *(uint4*)&a_sh[row * LSTR + sg * 8] = va;
            int gc = bn * 128 + row;            // always < 2304
            uint4 vb4 = *(const uint4*)(Bm + gc * 768 + kt * 64 + sg * 8);
            *(uint4*)&b_sh[row * LSTR + sg * 8] = vb4;
        }
        __syncthreads();
#pragma unroll
        for (int ks = 0; ks < 2; ++ks) {        // two K=32 MFMA steps inside BK=64
            bf8 af[4], bfr[4];
#pragma unroll
            for (int i = 0; i < 4; ++i)
                af[i] = *(const bf8*)&a_sh[(wm * 64 + i * 16 + ln) * LSTR + ks * 32 + quad * 8];
#pragma unroll
            for (int j = 0; j < 4; ++j)
                bfr[j] = *(const bf8*)&b_sh[(wn * 64 + j * 16 + ln) * LSTR + ks * 32 + quad * 8];
#pragma unroll
            for (int i = 0; i < 4; ++i)
#pragma unroll
                for (int j = 0; j < 4; ++j)
                    acc[i][j] = __builtin_amdgcn_mfma_f32_16x16x32_bf16(af[i], bfr[j], acc[i][j], 0, 0, 0);
        }
    }

    // epilogue: C/D layout col=lane&15, row=quad*4+reg (m89-verified)
#pragma unroll
    for (int i = 0; i < 4; ++i) {
#pragma unroll
        for (int r = 0; r < 4; ++r) {
            int row_g = bm * 128 + wm * 64 + i * 16 + quad * 4 + r;
            if (row_g >= M_TOT) continue;
            int bb = row_g / 197, tok = row_g - bb * 197;
#pragma unroll
            for (int j = 0; j < 4; ++j) {
                int col_g = bn * 128 + wn * 64 + j * 16 + ln;
                int which = col_g / 768, cc = col_g - which * 768;
                int h = cc >> 6, d = cc & 63;
                float v = acc[i][j][r];
                if (which == 0) {
                    v = (v + qb[cc]) * 0.125f;
                    q_ws[((bb * 12 + h) * 197 + tok) * 64 + d] = f2bf(v);
                } else if (which == 1) {
                    k_ws[((bb * 12 + h) * 197 + tok) * 64 + d] = f2bf(v);
                } else {
                    v += vbias[cc];
                    v_ws[((bb * 12 + h) * 64 + d) * 224 + tok] = f2bf(v);  // transposed store
                }
            }
        }
    }
}

// ---------------- attention: one block per (b,h), 4 waves, full-row softmax ----------------
__global__ __launch_bounds__(256) void k_attn(const unsigned short* __restrict__ q_ws,
                                              const unsigned short* __restrict__ k_ws,
                                              const unsigned short* __restrict__ v_ws,
                                              const float* __restrict__ bias_hqk,
                                              unsigned short* __restrict__ att_ws) {
    __shared__ unsigned short p_sh[4 * 16 * 232];   // per-wave 16x232 bf16 P slice
    const int bh = blockIdx.x;
    const int b = bh / 12, h = bh - b * 12;
    const int t = threadIdx.x, w = t >> 6, lane = t & 63, ln = lane & 15, quad = lane >> 4;
    const unsigned short* qp = q_ws + (size_t)bh * 197 * 64;
    const unsigned short* kp = k_ws + (size_t)bh * 197 * 64;
    const unsigned short* vp = v_ws + (size_t)bh * 64 * 224;
    const float* bp = bias_hqk + h * 197 * 197;
    unsigned short* psl = p_sh + w * 16 * 232;

    for (int mt = w; mt < 13; mt += 4) {
        int mrow = mt * 16 + ln;
        int mc = mrow < 197 ? mrow : 196;   // clamped pad rows; discarded at store
        bf8 qa[2];
#pragma unroll
        for (int ks = 0; ks < 2; ++ks) qa[ks] = *(const bf8*)(qp + mc * 64 + ks * 32 + quad * 8);

        f4 acc[13];
#pragma unroll
        for (int nt = 0; nt < 13; ++nt) acc[nt] = (f4){0.f, 0.f, 0.f, 0.f};
#pragma unroll
        for (int nt = 0; nt < 13; ++nt) {
            int nrow = nt * 16 + ln;
            int nc = nrow < 197 ? nrow : 196;
#pragma unroll
            for (int ks = 0; ks < 2; ++ks) {
                bf8 kb = *(const bf8*)(kp + nc * 64 + ks * 32 + quad * 8);
                acc[nt] = __builtin_amdgcn_mfma_f32_16x16x32_bf16(qa[ks], kb, acc[nt], 0, 0, 0);
            }
        }

        // bias add + key mask + row max (rows live in one 16-lane group)
        int qi[4];
#pragma unroll
        for (int r = 0; r < 4; ++r) { int q0 = mt * 16 + quad * 4 + r; qi[r] = q0 < 197 ? q0 : 196; }
        float mx[4] = {-3.0e38f, -3.0e38f, -3.0e38f, -3.0e38f};
#pragma unroll
        for (int nt = 0; nt < 13; ++nt) {
            int kidx = nt * 16 + ln;
#pragma unroll
            for (int r = 0; r < 4; ++r) {
                float s = (kidx < 197) ? (acc[nt][r] + bp[qi[r] * 197 + kidx]) : -3.0e38f;
                acc[nt][r] = s;
                mx[r] = fmaxf(mx[r], s);
            }
        }
#pragma unroll
        for (int r = 0; r < 4; ++r)
#pragma unroll
            for (int off = 1; off < 16; off <<= 1)
                mx[r] = fmaxf(mx[r], __shfl_xor(mx[r], off, 64));

        float sum[4] = {0.f, 0.f, 0.f, 0.f};
#pragma unroll
        for (int nt = 0; nt < 13; ++nt)
#pragma unroll
            for (int r = 0; r < 4; ++r) {
                float p = __expf(acc[nt][r] - mx[r]);
                acc[nt][r] = p;
                sum[r] += p;
            }
#pragma unroll
        for (int r = 0; r < 4; ++r)
#pragma unroll
            for (int off = 1; off < 16; off <<= 1)
                sum[r] += __shfl_xor(sum[r], off, 64);
        float inv[4];
#pragma unroll
        for (int r = 0; r < 4; ++r) inv[r] = 1.0f / sum[r];

        // P -> LDS (A-operand layout source), zero K-pad cols 208..223
#pragma unroll
        for (int nt = 0; nt < 13; ++nt)
#pragma unroll
            for (int r = 0; r < 4; ++r)
                psl[(quad * 4 + r) * 232 + nt * 16 + ln] = f2bf(acc[nt][r] * inv[r]);
        for (int i = lane; i < 256; i += 64)
            psl[(i >> 4) * 232 + 208 + (i & 15)] = 0;
        __asm__ __volatile__("s_waitcnt lgkmcnt(0)" ::: "memory");

        // PV: M=16, N=64 (4 subtiles), K=224
#pragma unroll
        for (int j = 0; j < 4; ++j) {
            f4 o = (f4){0.f, 0.f, 0.f, 0.f};
#pragma unroll
            for (int ks = 0; ks < 7; ++ks) {
                bf8 pa = *(const bf8*)&psl[ln * 232 + ks * 32 + quad * 8];
                bf8 vf = *(const bf8*)(vp + (j * 16 + ln) * 224 + ks * 32 + quad * 8);
                o = __builtin_amdgcn_mfma_f32_16x16x32_bf16(pa, vf, o, 0, 0, 0);
            }
#pragma unroll
            for (int r = 0; r < 4; ++r) {
                int tok = mt * 16 + quad * 4 + r;
                if (tok < 197)
                    att_ws[((size_t)b * 197 + tok) * 768 + h * 64 + j * 16 + ln] = f2bf(o[r]);
            }
        }
        __asm__ __volatile__("s_waitcnt lgkmcnt(0)" ::: "memory");
    }
}

// ---------------- proj GEMM: (12608x768) @ (768x768)^T + bias -> fp32 out ----------------
__global__ __launch_bounds__(256) void k_proj(const unsigned short* __restrict__ A,
                                              const unsigned short* __restrict__ Bm,
                                              const float* __restrict__ pb,
                                              float* __restrict__ out) {
    __shared__ unsigned short a_sh[128 * LSTR];
    __shared__ unsigned short b_sh[128 * LSTR];
    const int t = threadIdx.x;
    const int w = t >> 6, lane = t & 63, ln = lane & 15, quad = lane >> 4;
    const int wm = w & 1, wn = w >> 1;
    const int bm = blockIdx.x, bn = blockIdx.y;

    f4 acc[4][4] = {};

    for (int kt = 0; kt < 12; ++kt) {           // BK = 64
        __syncthreads();
#pragma unroll
        for (int it = 0; it < 4; ++it) {
            int s = t + it * 256;
            int row = s >> 3, sg = s & 7;
            int gr = bm * 128 + row;
            uint4 va = make_uint4(0, 0, 0, 0);
            if (gr < M_TOT) va = *(const uint4*)(A + gr * 768 + kt * 64 + sg * 8);
            *(uint4*)&a_sh[row * LSTR + sg * 8] = va;
            int gc = bn * 128 + row;            // < 768
            uint4 vb4 = *(const uint4*)(Bm + gc * 768 + kt * 64 + sg * 8);
            *(uint4*)&b_sh[row * LSTR + sg * 8] = vb4;
        }
        __syncthreads();
#pragma unroll
        for (int ks = 0; ks < 2; ++ks) {
            bf8 af[4], bfr[4];
#pragma unroll
            for (int i = 0; i < 4; ++i)
                af[i] = *(const bf8*)&a_sh[(wm * 64 + i * 16 + ln) * LSTR + ks * 32 + quad * 8];
#pragma unroll
            for (int j = 0; j < 4; ++j)
                bfr[j] = *(const bf8*)&b_sh[(wn * 64 + j * 16 + ln) * LSTR + ks * 32 + quad * 8];
#pragma unroll
            for (int i = 0; i < 4; ++i)
#pragma unroll
                for (int j = 0; j < 4; ++j)
                    acc[i][j] = __builtin_amdgcn_mfma_f32_16x16x32_bf16(af[i], bfr[j], acc[i][j], 0, 0, 0);
        }
    }

#pragma unroll
    for (int i = 0; i < 4; ++i) {
#pragma unroll
        for (int r = 0; r < 4; ++r) {
            int row_g = bm * 128 + wm * 64 + i * 16 + quad * 4 + r;
            if (row_g >= M_TOT) continue;
#pragma unroll
            for (int j = 0; j < 4; ++j) {
                int col_g = bn * 128 + wn * 64 + j * 16 + ln;
                out[(size_t)row_g * 768 + col_g] = acc[i][j][r] + pb[col_g];
            }
        }
    }
}

extern "C" void kernel_launch(void* const* d_in, const int* in_sizes, int n_in,
                              void* d_out, int out_size, void* d_ws, size_t ws_size,
                              hipStream_t stream) {
    const float* x     = (const float*)d_in[0];
    const float* qkvw  = (const float*)d_in[1];
    const float* qb    = (const float*)d_in[2];
    const float* vb    = (const float*)d_in[3];
    const float* rpb   = (const float*)d_in[4];
    const float* projw = (const float*)d_in[5];
    const float* pb    = (const float*)d_in[6];
    const int*   ridx  = (const int*)d_in[7];
    float* out = (float*)d_out;

    char* ws = (char*)d_ws;
    size_t off = 0;
    auto alloc = [&](size_t bytes) -> void* {
        void* p = ws + off;
        off = (off + bytes + 255) & ~(size_t)255;
        return p;
    };
    unsigned short* x_bf     = (unsigned short*)alloc((size_t)M_TOT * DIM_ * 2);
    unsigned short* qkvw_bf  = (unsigned short*)alloc((size_t)3 * DIM_ * DIM_ * 2);
    unsigned short* projw_bf = (unsigned short*)alloc((size_t)DIM_ * DIM_ * 2);
    float*          bias_h   = (float*)alloc((size_t)H_ * N_ * N_ * 4);
    unsigned short* q_ws     = (unsigned short*)alloc((size_t)B_ * H_ * N_ * HD_ * 2);
    unsigned short* k_ws     = (unsigned short*)alloc((size_t)B_ * H_ * N_ * HD_ * 2);
    unsigned short* v_ws     = (unsigned short*)alloc((size_t)B_ * H_ * HD_ * 224 * 2);
    unsigned short* att_ws   = (unsigned short*)alloc((size_t)M_TOT * DIM_ * 2);
    (void)ws_size; (void)in_sizes; (void)n_in; (void)out_size;

    k_prep<<<1200, 256, 0, stream>>>(x, qkvw, projw, rpb, ridx,
                                     x_bf, qkvw_bf, projw_bf, bias_h, v_ws);
    k_qkv<<<dim3(99, 18), 256, 0, stream>>>(x_bf, qkvw_bf, qb, vb, q_ws, k_ws, v_ws);
    k_attn<<<768, 256, 0, stream>>>(q_ws, k_ws, v_ws, bias_h, att_ws);
    k_proj<<<dim3(99, 6), 256, 0, stream>>>(att_ws, projw_bf, pb, out);
}

// Round 3
// 348.932 us; speedup vs baseline: 1.1636x; 1.1636x over previous
//
#include <hip/hip_runtime.h>

// AttentionWindow (BEiT windowed attention), MI355X gfx950.
// B=64 N=197 DIM=768 H=12 hd=64. bf16 MFMA (16x16x32), fp32 softmax.
// R3: k_qkv/k_proj staging via __builtin_amdgcn_global_load_lds width=16
//     (async DMA, no VGPR round-trip), source-side XOR bank swizzle,
//     XCD-aware panel-swizzled 1D grid for A-tile L2 residency.

#define B_    64
#define N_    197
#define DIM_  768
#define H_    12
#define HD_   64
#define M_TOT (B_ * N_)     // 12608

typedef __attribute__((ext_vector_type(8))) short bf8;
typedef __attribute__((ext_vector_type(4))) float f4;

__device__ __forceinline__ unsigned short f2bf(float f) {
    unsigned u = __float_as_uint(f);
    u = (u + 0x7fffu + ((u >> 16) & 1u)) >> 16;
    return (unsigned short)u;
}

// async global->LDS 16B per lane; LDS dest = wave-uniform base + lane*16 (m104/m108)
__device__ __forceinline__ void gl2lds16(const unsigned short* g, unsigned short* l) {
    __builtin_amdgcn_global_load_lds(
        (const __attribute__((address_space(1))) void*)g,
        (__attribute__((address_space(3))) void*)l, 16, 0, 0);
}

// ---------------- prep: fp32->bf16 converts, bias gather, vT pad zero ----------------
__global__ void k_prep(const float* __restrict__ x, const float* __restrict__ qkvw,
                       const float* __restrict__ projw, const float* __restrict__ rpb,
                       const int* __restrict__ relidx,
                       unsigned short* __restrict__ x_bf, unsigned short* __restrict__ qkvw_bf,
                       unsigned short* __restrict__ projw_bf, float* __restrict__ bias_hqk,
                       unsigned short* __restrict__ v_ws) {
    const int T = gridDim.x * blockDim.x;
    const int tid = blockIdx.x * blockDim.x + threadIdx.x;
    for (int i = tid; i < M_TOT * DIM_; i += T) x_bf[i] = f2bf(x[i]);
    for (int i = tid; i < 3 * DIM_ * DIM_; i += T) qkvw_bf[i] = f2bf(qkvw[i]);
    for (int i = tid; i < DIM_ * DIM_; i += T) projw_bf[i] = f2bf(projw[i]);
    for (int i = tid; i < H_ * N_ * N_; i += T) {
        int h = i / (N_ * N_), qk = i - h * (N_ * N_);
        bias_hqk[i] = rpb[relidx[qk] * H_ + h];
    }
    // zero vT columns 197..223 (PV K-padding)
    for (int i = tid; i < B_ * H_ * HD_ * 27; i += T) {
        int row = i / 27, c = 197 + (i - row * 27);
        v_ws[row * 224 + c] = 0;
    }
}

// ---------------- QKV GEMM: (12608x768) @ (2304x768)^T, scatter epilogue ----------------
// LDS tile 128x64 bf16, unpadded stride 64 (global_load_lds requirement).
// Bank fix: LDS slot (row, c8) holds global chunk c8 ^ (row&7); reader xors back.
__global__ __launch_bounds__(256) void k_qkv(const unsigned short* __restrict__ A,
                                             const unsigned short* __restrict__ Bm,
                                             const float* __restrict__ qb, const float* __restrict__ vbias,
                                             unsigned short* __restrict__ q_ws,
                                             unsigned short* __restrict__ k_ws,
                                             unsigned short* __restrict__ v_ws) {
    __shared__ unsigned short a_sh[128 * 64];
    __shared__ unsigned short b_sh[128 * 64];
    const int t = threadIdx.x;
    const int w = t >> 6, lane = t & 63, ln = lane & 15, quad = lane >> 4;
    const int wm = w & 1, wn = w >> 1;

    // panel swizzle: 8 bm x 18 bn per panel, bm fastest -> gid%8 (XCD) pins one bm
    const int gid = blockIdx.x;
    const int panel = gid / 144, rem = gid - panel * 144;
    const int pm0 = panel * 8;
    const int psz = (99 - pm0 < 8) ? (99 - pm0) : 8;
    const int bm = pm0 + rem % psz;
    const int bn = rem / psz;

    const int rsub = lane >> 3;                  // 0..7 row within 8-row chunk
    const int src8 = (lane & 7) ^ rsub;          // swizzled source chunk

    f4 acc[4][4] = {};

    for (int kt = 0; kt < 12; ++kt) {           // BK = 64
        __syncthreads();
#pragma unroll
        for (int c = 0; c < 4; ++c) {
            int rb = w * 32 + c * 8;            // wave-uniform chunk base row
            int gr = bm * 128 + rb + rsub;
            if (gr > M_TOT - 1) gr = M_TOT - 1; // clamp (pad rows discarded later)
            gl2lds16(A + (size_t)gr * 768 + kt * 64 + (src8 << 3), &a_sh[rb * 64]);
            int gc = bn * 128 + rb + rsub;      // always < 2304
            gl2lds16(Bm + (size_t)gc * 768 + kt * 64 + (src8 << 3), &b_sh[rb * 64]);
        }
        __syncthreads();
#pragma unroll
        for (int ks = 0; ks < 2; ++ks) {
            bf8 af[4], bfr[4];
#pragma unroll
            for (int i = 0; i < 4; ++i)
                af[i] = *(const bf8*)&a_sh[((wm * 64 + i * 16 + ln) << 6) +
                                           ((((ks << 2) + quad) ^ (ln & 7)) << 3)];
#pragma unroll
            for (int j = 0; j < 4; ++j)
                bfr[j] = *(const bf8*)&b_sh[((wn * 64 + j * 16 + ln) << 6) +
                                            ((((ks << 2) + quad) ^ (ln & 7)) << 3)];
#pragma unroll
            for (int i = 0; i < 4; ++i)
#pragma unroll
                for (int j = 0; j < 4; ++j)
                    acc[i][j] = __builtin_amdgcn_mfma_f32_16x16x32_bf16(af[i], bfr[j], acc[i][j], 0, 0, 0);
        }
    }

    // epilogue: C/D layout col=lane&15, row=quad*4+reg (m89-verified)
#pragma unroll
    for (int i = 0; i < 4; ++i) {
#pragma unroll
        for (int r = 0; r < 4; ++r) {
            int row_g = bm * 128 + wm * 64 + i * 16 + quad * 4 + r;
            if (row_g >= M_TOT) continue;
            int bb = row_g / 197, tok = row_g - bb * 197;
#pragma unroll
            for (int j = 0; j < 4; ++j) {
                int col_g = bn * 128 + wn * 64 + j * 16 + ln;
                int which = col_g / 768, cc = col_g - which * 768;
                int h = cc >> 6, d = cc & 63;
                float v = acc[i][j][r];
                if (which == 0) {
                    v = (v + qb[cc]) * 0.125f;
                    q_ws[((bb * 12 + h) * 197 + tok) * 64 + d] = f2bf(v);
                } else if (which == 1) {
                    k_ws[((bb * 12 + h) * 197 + tok) * 64 + d] = f2bf(v);
                } else {
                    v += vbias[cc];
                    v_ws[((bb * 12 + h) * 64 + d) * 224 + tok] = f2bf(v);  // transposed store
                }
            }
        }
    }
}

// ---------------- attention: one block per (b,h), 4 waves, full-row softmax ----------------
__global__ __launch_bounds__(256) void k_attn(const unsigned short* __restrict__ q_ws,
                                              const unsigned short* __restrict__ k_ws,
                                              const unsigned short* __restrict__ v_ws,
                                              const float* __restrict__ bias_hqk,
                                              unsigned short* __restrict__ att_ws) {
    __shared__ unsigned short p_sh[4 * 16 * 232];   // per-wave 16x232 bf16 P slice
    const int bh = blockIdx.x;
    const int b = bh / 12, h = bh - b * 12;
    const int t = threadIdx.x, w = t >> 6, lane = t & 63, ln = lane & 15, quad = lane >> 4;
    const unsigned short* qp = q_ws + (size_t)bh * 197 * 64;
    const unsigned short* kp = k_ws + (size_t)bh * 197 * 64;
    const unsigned short* vp = v_ws + (size_t)bh * 64 * 224;
    const float* bp = bias_hqk + h * 197 * 197;
    unsigned short* psl = p_sh + w * 16 * 232;

    for (int mt = w; mt < 13; mt += 4) {
        int mrow = mt * 16 + ln;
        int mc = mrow < 197 ? mrow : 196;   // clamped pad rows; discarded at store
        bf8 qa[2];
#pragma unroll
        for (int ks = 0; ks < 2; ++ks) qa[ks] = *(const bf8*)(qp + mc * 64 + ks * 32 + quad * 8);

        f4 acc[13];
#pragma unroll
        for (int nt = 0; nt < 13; ++nt) acc[nt] = (f4){0.f, 0.f, 0.f, 0.f};
#pragma unroll
        for (int nt = 0; nt < 13; ++nt) {
            int nrow = nt * 16 + ln;
            int nc = nrow < 197 ? nrow : 196;
#pragma unroll
            for (int ks = 0; ks < 2; ++ks) {
                bf8 kb = *(const bf8*)(kp + nc * 64 + ks * 32 + quad * 8);
                acc[nt] = __builtin_amdgcn_mfma_f32_16x16x32_bf16(qa[ks], kb, acc[nt], 0, 0, 0);
            }
        }

        // bias add + key mask + row max (rows live in one 16-lane group)
        int qi[4];
#pragma unroll
        for (int r = 0; r < 4; ++r) { int q0 = mt * 16 + quad * 4 + r; qi[r] = q0 < 197 ? q0 : 196; }
        float mx[4] = {-3.0e38f, -3.0e38f, -3.0e38f, -3.0e38f};
#pragma unroll
        for (int nt = 0; nt < 13; ++nt) {
            int kidx = nt * 16 + ln;
#pragma unroll
            for (int r = 0; r < 4; ++r) {
                float s = (kidx < 197) ? (acc[nt][r] + bp[qi[r] * 197 + kidx]) : -3.0e38f;
                acc[nt][r] = s;
                mx[r] = fmaxf(mx[r], s);
            }
        }
#pragma unroll
        for (int r = 0; r < 4; ++r)
#pragma unroll
            for (int off = 1; off < 16; off <<= 1)
                mx[r] = fmaxf(mx[r], __shfl_xor(mx[r], off, 64));

        float sum[4] = {0.f, 0.f, 0.f, 0.f};
#pragma unroll
        for (int nt = 0; nt < 13; ++nt)
#pragma unroll
            for (int r = 0; r < 4; ++r) {
                float p = __expf(acc[nt][r] - mx[r]);
                acc[nt][r] = p;
                sum[r] += p;
            }
#pragma unroll
        for (int r = 0; r < 4; ++r)
#pragma unroll
            for (int off = 1; off < 16; off <<= 1)
                sum[r] += __shfl_xor(sum[r], off, 64);
        float inv[4];
#pragma unroll
        for (int r = 0; r < 4; ++r) inv[r] = 1.0f / sum[r];

        // P -> LDS (A-operand layout source), zero K-pad cols 208..223
#pragma unroll
        for (int nt = 0; nt < 13; ++nt)
#pragma unroll
            for (int r = 0; r < 4; ++r)
                psl[(quad * 4 + r) * 232 + nt * 16 + ln] = f2bf(acc[nt][r] * inv[r]);
        for (int i = lane; i < 256; i += 64)
            psl[(i >> 4) * 232 + 208 + (i & 15)] = 0;
        __asm__ __volatile__("s_waitcnt lgkmcnt(0)" ::: "memory");

        // PV: M=16, N=64 (4 subtiles), K=224
#pragma unroll
        for (int j = 0; j < 4; ++j) {
            f4 o = (f4){0.f, 0.f, 0.f, 0.f};
#pragma unroll
            for (int ks = 0; ks < 7; ++ks) {
                bf8 pa = *(const bf8*)&psl[ln * 232 + ks * 32 + quad * 8];
                bf8 vf = *(const bf8*)(vp + (j * 16 + ln) * 224 + ks * 32 + quad * 8);
                o = __builtin_amdgcn_mfma_f32_16x16x32_bf16(pa, vf, o, 0, 0, 0);
            }
#pragma unroll
            for (int r = 0; r < 4; ++r) {
                int tok = mt * 16 + quad * 4 + r;
                if (tok < 197)
                    att_ws[((size_t)b * 197 + tok) * 768 + h * 64 + j * 16 + ln] = f2bf(o[r]);
            }
        }
        __asm__ __volatile__("s_waitcnt lgkmcnt(0)" ::: "memory");
    }
}

// ---------------- proj GEMM: (12608x768) @ (768x768)^T + bias -> fp32 out ----------------
__global__ __launch_bounds__(256) void k_proj(const unsigned short* __restrict__ A,
                                              const unsigned short* __restrict__ Bm,
                                              const float* __restrict__ pb,
                                              float* __restrict__ out) {
    __shared__ unsigned short a_sh[128 * 64];
    __shared__ unsigned short b_sh[128 * 64];
    const int t = threadIdx.x;
    const int w = t >> 6, lane = t & 63, ln = lane & 15, quad = lane >> 4;
    const int wm = w & 1, wn = w >> 1;

    const int gid = blockIdx.x;                 // panels: 8 bm x 6 bn = 48
    const int panel = gid / 48, rem = gid - panel * 48;
    const int pm0 = panel * 8;
    const int psz = (99 - pm0 < 8) ? (99 - pm0) : 8;
    const int bm = pm0 + rem % psz;
    const int bn = rem / psz;

    const int rsub = lane >> 3;
    const int src8 = (lane & 7) ^ rsub;

    f4 acc[4][4] = {};

    for (int kt = 0; kt < 12; ++kt) {           // BK = 64
        __syncthreads();
#pragma unroll
        for (int c = 0; c < 4; ++c) {
            int rb = w * 32 + c * 8;
            int gr = bm * 128 + rb + rsub;
            if (gr > M_TOT - 1) gr = M_TOT - 1;
            gl2lds16(A + (size_t)gr * 768 + kt * 64 + (src8 << 3), &a_sh[rb * 64]);
            int gc = bn * 128 + rb + rsub;      // < 768
            gl2lds16(Bm + (size_t)gc * 768 + kt * 64 + (src8 << 3), &b_sh[rb * 64]);
        }
        __syncthreads();
#pragma unroll
        for (int ks = 0; ks < 2; ++ks) {
            bf8 af[4], bfr[4];
#pragma unroll
            for (int i = 0; i < 4; ++i)
                af[i] = *(const bf8*)&a_sh[((wm * 64 + i * 16 + ln) << 6) +
                                           ((((ks << 2) + quad) ^ (ln & 7)) << 3)];
#pragma unroll
            for (int j = 0; j < 4; ++j)
                bfr[j] = *(const bf8*)&b_sh[((wn * 64 + j * 16 + ln) << 6) +
                                            ((((ks << 2) + quad) ^ (ln & 7)) << 3)];
#pragma unroll
            for (int i = 0; i < 4; ++i)
#pragma unroll
                for (int j = 0; j < 4; ++j)
                    acc[i][j] = __builtin_amdgcn_mfma_f32_16x16x32_bf16(af[i], bfr[j], acc[i][j], 0, 0, 0);
        }
    }

#pragma unroll
    for (int i = 0; i < 4; ++i) {
#pragma unroll
        for (int r = 0; r < 4; ++r) {
            int row_g = bm * 128 + wm * 64 + i * 16 + quad * 4 + r;
            if (row_g >= M_TOT) continue;
#pragma unroll
            for (int j = 0; j < 4; ++j) {
                int col_g = bn * 128 + wn * 64 + j * 16 + ln;
                out[(size_t)row_g * 768 + col_g] = acc[i][j][r] + pb[col_g];
            }
        }
    }
}

extern "C" void kernel_launch(void* const* d_in, const int* in_sizes, int n_in,
                              void* d_out, int out_size, void* d_ws, size_t ws_size,
                              hipStream_t stream) {
    const float* x     = (const float*)d_in[0];
    const float* qkvw  = (const float*)d_in[1];
    const float* qb    = (const float*)d_in[2];
    const float* vb    = (const float*)d_in[3];
    const float* rpb   = (const float*)d_in[4];
    const float* projw = (const float*)d_in[5];
    const float* pb    = (const float*)d_in[6];
    const int*   ridx  = (const int*)d_in[7];
    float* out = (float*)d_out;

    char* ws = (char*)d_ws;
    size_t off = 0;
    auto alloc = [&](size_t bytes) -> void* {
        void* p = ws + off;
        off = (off + bytes + 255) & ~(size_t)255;
        return p;
    };
    unsigned short* x_bf     = (unsigned short*)alloc((size_t)M_TOT * DIM_ * 2);
    unsigned short* qkvw_bf  = (unsigned short*)alloc((size_t)3 * DIM_ * DIM_ * 2);
    unsigned short* projw_bf = (unsigned short*)alloc((size_t)DIM_ * DIM_ * 2);
    float*          bias_h   = (float*)alloc((size_t)H_ * N_ * N_ * 4);
    unsigned short* q_ws     = (unsigned short*)alloc((size_t)B_ * H_ * N_ * HD_ * 2);
    unsigned short* k_ws     = (unsigned short*)alloc((size_t)B_ * H_ * N_ * HD_ * 2);
    unsigned short* v_ws     = (unsigned short*)alloc((size_t)B_ * H_ * HD_ * 224 * 2);
    unsigned short* att_ws   = (unsigned short*)alloc((size_t)(M_TOT + 64) * DIM_ * 2); // +64 rows OOB-read pad
    (void)ws_size; (void)in_sizes; (void)n_in; (void)out_size;

    k_prep<<<1200, 256, 0, stream>>>(x, qkvw, projw, rpb, ridx,
                                     x_bf, qkvw_bf, projw_bf, bias_h, v_ws);
    k_qkv<<<1782, 256, 0, stream>>>(x_bf, qkvw_bf, qb, vb, q_ws, k_ws, v_ws);
    k_attn<<<768, 256, 0, stream>>>(q_ws, k_ws, v_ws, bias_h, att_ws);
    k_proj<<<594, 256, 0, stream>>>(att_ws, projw_bf, pb, out);
}

// Round 4
// 333.665 us; speedup vs baseline: 1.2168x; 1.0458x over previous
//
#include <hip/hip_runtime.h>

// AttentionWindow (BEiT windowed attention), MI355X gfx950.
// B=64 N=197 DIM=768 H=12 hd=64. bf16 MFMA (16x16x32), fp32 softmax.
// R4: k_qkv/k_proj K-loop restructured to double-buffered async staging:
//     DMA for tile kt+1 issued right after the barrier, compute on tile kt
//     overlaps the flight; 1 barrier/kt instead of 2. Buffers are distinct
//     __shared__ arrays (a0/a1/b0/b1) so compiler can't alias DMA vs ds_read.

#define B_    64
#define N_    197
#define DIM_  768
#define H_    12
#define HD_   64
#define M_TOT (B_ * N_)     // 12608

typedef __attribute__((ext_vector_type(8))) short bf8;
typedef __attribute__((ext_vector_type(4))) float f4;

__device__ __forceinline__ unsigned short f2bf(float f) {
    unsigned u = __float_as_uint(f);
    u = (u + 0x7fffu + ((u >> 16) & 1u)) >> 16;
    return (unsigned short)u;
}

// async global->LDS 16B per lane; LDS dest = wave-uniform base + lane*16 (m104/m108)
__device__ __forceinline__ void gl2lds16(const unsigned short* g, unsigned short* l) {
    __builtin_amdgcn_global_load_lds(
        (const __attribute__((address_space(1))) void*)g,
        (__attribute__((address_space(3))) void*)l, 16, 0, 0);
}

// stage one 128x64 A-tile + 128x64 B-tile (bank-swizzled on the source side)
__device__ __forceinline__ void stage_tiles(const unsigned short* __restrict__ A,
                                            const unsigned short* __restrict__ Bm,
                                            int bm, int bn, int kt, int w, int rsub, int src8,
                                            unsigned short* a_l, unsigned short* b_l) {
#pragma unroll
    for (int c = 0; c < 4; ++c) {
        int rb = w * 32 + c * 8;                // wave-uniform chunk base row
        int gr = bm * 128 + rb + rsub;
        if (gr > M_TOT - 1) gr = M_TOT - 1;     // clamp (pad rows discarded later)
        gl2lds16(A + (size_t)gr * 768 + kt * 64 + (src8 << 3), &a_l[rb * 64]);
        int gc = bn * 128 + rb + rsub;
        gl2lds16(Bm + (size_t)gc * 768 + kt * 64 + (src8 << 3), &b_l[rb * 64]);
    }
}

// one BK=64 compute phase (two K=32 MFMA steps), 64x64 per-wave subtile
__device__ __forceinline__ void compute_tiles(const unsigned short* a_l, const unsigned short* b_l,
                                              int wm, int wn, int ln, int quad, f4 (*acc)[4]) {
#pragma unroll
    for (int ks = 0; ks < 2; ++ks) {
        bf8 af[4], bfr[4];
#pragma unroll
        for (int i = 0; i < 4; ++i)
            af[i] = *(const bf8*)&a_l[((wm * 64 + i * 16 + ln) << 6) +
                                      ((((ks << 2) + quad) ^ (ln & 7)) << 3)];
#pragma unroll
        for (int j = 0; j < 4; ++j)
            bfr[j] = *(const bf8*)&b_l[((wn * 64 + j * 16 + ln) << 6) +
                                       ((((ks << 2) + quad) ^ (ln & 7)) << 3)];
#pragma unroll
        for (int i = 0; i < 4; ++i)
#pragma unroll
            for (int j = 0; j < 4; ++j)
                acc[i][j] = __builtin_amdgcn_mfma_f32_16x16x32_bf16(af[i], bfr[j], acc[i][j], 0, 0, 0);
    }
}

// ---------------- prep: fp32->bf16 converts, bias gather, vT pad zero ----------------
__global__ void k_prep(const float* __restrict__ x, const float* __restrict__ qkvw,
                       const float* __restrict__ projw, const float* __restrict__ rpb,
                       const int* __restrict__ relidx,
                       unsigned short* __restrict__ x_bf, unsigned short* __restrict__ qkvw_bf,
                       unsigned short* __restrict__ projw_bf, float* __restrict__ bias_hqk,
                       unsigned short* __restrict__ v_ws) {
    const int T = gridDim.x * blockDim.x;
    const int tid = blockIdx.x * blockDim.x + threadIdx.x;
    for (int i = tid; i < M_TOT * DIM_; i += T) x_bf[i] = f2bf(x[i]);
    for (int i = tid; i < 3 * DIM_ * DIM_; i += T) qkvw_bf[i] = f2bf(qkvw[i]);
    for (int i = tid; i < DIM_ * DIM_; i += T) projw_bf[i] = f2bf(projw[i]);
    for (int i = tid; i < H_ * N_ * N_; i += T) {
        int h = i / (N_ * N_), qk = i - h * (N_ * N_);
        bias_hqk[i] = rpb[relidx[qk] * H_ + h];
    }
    // zero vT columns 197..223 (PV K-padding)
    for (int i = tid; i < B_ * H_ * HD_ * 27; i += T) {
        int row = i / 27, c = 197 + (i - row * 27);
        v_ws[row * 224 + c] = 0;
    }
}

// ---------------- QKV GEMM: (12608x768) @ (2304x768)^T, scatter epilogue ----------------
__global__ __launch_bounds__(256) void k_qkv(const unsigned short* __restrict__ A,
                                             const unsigned short* __restrict__ Bm,
                                             const float* __restrict__ qb, const float* __restrict__ vbias,
                                             unsigned short* __restrict__ q_ws,
                                             unsigned short* __restrict__ k_ws,
                                             unsigned short* __restrict__ v_ws) {
    __shared__ unsigned short a0[128 * 64], a1[128 * 64];
    __shared__ unsigned short b0[128 * 64], b1[128 * 64];
    const int t = threadIdx.x;
    const int w = t >> 6, lane = t & 63, ln = lane & 15, quad = lane >> 4;
    const int wm = w & 1, wn = w >> 1;

    // panel swizzle: 8 bm x 18 bn per panel, bm fastest -> gid%8 (XCD) pins one bm
    const int gid = blockIdx.x;
    const int panel = gid / 144, rem = gid - panel * 144;
    const int pm0 = panel * 8;
    const int psz = (99 - pm0 < 8) ? (99 - pm0) : 8;
    const int bm = pm0 + rem % psz;
    const int bn = rem / psz;

    const int rsub = lane >> 3;                  // 0..7 row within 8-row chunk
    const int src8 = (lane & 7) ^ rsub;          // swizzled source chunk

    f4 acc[4][4] = {};

    stage_tiles(A, Bm, bm, bn, 0, w, rsub, src8, a0, b0);
#pragma unroll
    for (int kt2 = 0; kt2 < 12; kt2 += 2) {
        __syncthreads();                         // drains buf0 loads (issued 1 phase ago)
        if (kt2 + 1 < 12) stage_tiles(A, Bm, bm, bn, kt2 + 1, w, rsub, src8, a1, b1);
        compute_tiles(a0, b0, wm, wn, ln, quad, acc);
        __syncthreads();                         // drains buf1 loads
        if (kt2 + 2 < 12) stage_tiles(A, Bm, bm, bn, kt2 + 2, w, rsub, src8, a0, b0);
        if (kt2 + 1 < 12) compute_tiles(a1, b1, wm, wn, ln, quad, acc);
    }

    // epilogue: C/D layout col=lane&15, row=quad*4+reg (m89-verified)
#pragma unroll
    for (int i = 0; i < 4; ++i) {
#pragma unroll
        for (int r = 0; r < 4; ++r) {
            int row_g = bm * 128 + wm * 64 + i * 16 + quad * 4 + r;
            if (row_g >= M_TOT) continue;
            int bb = row_g / 197, tok = row_g - bb * 197;
#pragma unroll
            for (int j = 0; j < 4; ++j) {
                int col_g = bn * 128 + wn * 64 + j * 16 + ln;
                int which = col_g / 768, cc = col_g - which * 768;
                int h = cc >> 6, d = cc & 63;
                float v = acc[i][j][r];
                if (which == 0) {
                    v = (v + qb[cc]) * 0.125f;
                    q_ws[((bb * 12 + h) * 197 + tok) * 64 + d] = f2bf(v);
                } else if (which == 1) {
                    k_ws[((bb * 12 + h) * 197 + tok) * 64 + d] = f2bf(v);
                } else {
                    v += vbias[cc];
                    v_ws[((bb * 12 + h) * 64 + d) * 224 + tok] = f2bf(v);  // transposed store
                }
            }
        }
    }
}

// ---------------- attention: one block per (b,h), 4 waves, full-row softmax ----------------
__global__ __launch_bounds__(256) void k_attn(const unsigned short* __restrict__ q_ws,
                                              const unsigned short* __restrict__ k_ws,
                                              const unsigned short* __restrict__ v_ws,
                                              const float* __restrict__ bias_hqk,
                                              unsigned short* __restrict__ att_ws) {
    __shared__ unsigned short p_sh[4 * 16 * 232];   // per-wave 16x232 bf16 P slice
    const int bh = blockIdx.x;
    const int b = bh / 12, h = bh - b * 12;
    const int t = threadIdx.x, w = t >> 6, lane = t & 63, ln = lane & 15, quad = lane >> 4;
    const unsigned short* qp = q_ws + (size_t)bh * 197 * 64;
    const unsigned short* kp = k_ws + (size_t)bh * 197 * 64;
    const unsigned short* vp = v_ws + (size_t)bh * 64 * 224;
    const float* bp = bias_hqk + h * 197 * 197;
    unsigned short* psl = p_sh + w * 16 * 232;

    for (int mt = w; mt < 13; mt += 4) {
        int mrow = mt * 16 + ln;
        int mc = mrow < 197 ? mrow : 196;   // clamped pad rows; discarded at store
        bf8 qa[2];
#pragma unroll
        for (int ks = 0; ks < 2; ++ks) qa[ks] = *(const bf8*)(qp + mc * 64 + ks * 32 + quad * 8);

        f4 acc[13];
#pragma unroll
        for (int nt = 0; nt < 13; ++nt) acc[nt] = (f4){0.f, 0.f, 0.f, 0.f};
#pragma unroll
        for (int nt = 0; nt < 13; ++nt) {
            int nrow = nt * 16 + ln;
            int nc = nrow < 197 ? nrow : 196;
#pragma unroll
            for (int ks = 0; ks < 2; ++ks) {
                bf8 kb = *(const bf8*)(kp + nc * 64 + ks * 32 + quad * 8);
                acc[nt] = __builtin_amdgcn_mfma_f32_16x16x32_bf16(qa[ks], kb, acc[nt], 0, 0, 0);
            }
        }

        // bias add + key mask + row max (rows live in one 16-lane group)
        int qi[4];
#pragma unroll
        for (int r = 0; r < 4; ++r) { int q0 = mt * 16 + quad * 4 + r; qi[r] = q0 < 197 ? q0 : 196; }
        float mx[4] = {-3.0e38f, -3.0e38f, -3.0e38f, -3.0e38f};
#pragma unroll
        for (int nt = 0; nt < 13; ++nt) {
            int kidx = nt * 16 + ln;
#pragma unroll
            for (int r = 0; r < 4; ++r) {
                float s = (kidx < 197) ? (acc[nt][r] + bp[qi[r] * 197 + kidx]) : -3.0e38f;
                acc[nt][r] = s;
                mx[r] = fmaxf(mx[r], s);
            }
        }
#pragma unroll
        for (int r = 0; r < 4; ++r)
#pragma unroll
            for (int off = 1; off < 16; off <<= 1)
                mx[r] = fmaxf(mx[r], __shfl_xor(mx[r], off, 64));

        float sum[4] = {0.f, 0.f, 0.f, 0.f};
#pragma unroll
        for (int nt = 0; nt < 13; ++nt)
#pragma unroll
            for (int r = 0; r < 4; ++r) {
                float p = __expf(acc[nt][r] - mx[r]);
                acc[nt][r] = p;
                sum[r] += p;
            }
#pragma unroll
        for (int r = 0; r < 4; ++r)
#pragma unroll
            for (int off = 1; off < 16; off <<= 1)
                sum[r] += __shfl_xor(sum[r], off, 64);
        float inv[4];
#pragma unroll
        for (int r = 0; r < 4; ++r) inv[r] = 1.0f / sum[r];

        // P -> LDS (A-operand layout source), zero K-pad cols 208..223
#pragma unroll
        for (int nt = 0; nt < 13; ++nt)
#pragma unroll
            for (int r = 0; r < 4; ++r)
                psl[(quad * 4 + r) * 232 + nt * 16 + ln] = f2bf(acc[nt][r] * inv[r]);
        for (int i = lane; i < 256; i += 64)
            psl[(i >> 4) * 232 + 208 + (i & 15)] = 0;
        __asm__ __volatile__("s_waitcnt lgkmcnt(0)" ::: "memory");

        // PV: M=16, N=64 (4 subtiles), K=224
#pragma unroll
        for (int j = 0; j < 4; ++j) {
            f4 o = (f4){0.f, 0.f, 0.f, 0.f};
#pragma unroll
            for (int ks = 0; ks < 7; ++ks) {
                bf8 pa = *(const bf8*)&psl[ln * 232 + ks * 32 + quad * 8];
                bf8 vf = *(const bf8*)(vp + (j * 16 + ln) * 224 + ks * 32 + quad * 8);
                o = __builtin_amdgcn_mfma_f32_16x16x32_bf16(pa, vf, o, 0, 0, 0);
            }
#pragma unroll
            for (int r = 0; r < 4; ++r) {
                int tok = mt * 16 + quad * 4 + r;
                if (tok < 197)
                    att_ws[((size_t)b * 197 + tok) * 768 + h * 64 + j * 16 + ln] = f2bf(o[r]);
            }
        }
        __asm__ __volatile__("s_waitcnt lgkmcnt(0)" ::: "memory");
    }
}

// ---------------- proj GEMM: (12608x768) @ (768x768)^T + bias -> fp32 out ----------------
__global__ __launch_bounds__(256) void k_proj(const unsigned short* __restrict__ A,
                                              const unsigned short* __restrict__ Bm,
                                              const float* __restrict__ pb,
                                              float* __restrict__ out) {
    __shared__ unsigned short a0[128 * 64], a1[128 * 64];
    __shared__ unsigned short b0[128 * 64], b1[128 * 64];
    const int t = threadIdx.x;
    const int w = t >> 6, lane = t & 63, ln = lane & 15, quad = lane >> 4;
    const int wm = w & 1, wn = w >> 1;

    const int gid = blockIdx.x;                 // panels: 8 bm x 6 bn = 48
    const int panel = gid / 48, rem = gid - panel * 48;
    const int pm0 = panel * 8;
    const int psz = (99 - pm0 < 8) ? (99 - pm0) : 8;
    const int bm = pm0 + rem % psz;
    const int bn = rem / psz;

    const int rsub = lane >> 3;
    const int src8 = (lane & 7) ^ rsub;

    f4 acc[4][4] = {};

    stage_tiles(A, Bm, bm, bn, 0, w, rsub, src8, a0, b0);
#pragma unroll
    for (int kt2 = 0; kt2 < 12; kt2 += 2) {
        __syncthreads();
        if (kt2 + 1 < 12) stage_tiles(A, Bm, bm, bn, kt2 + 1, w, rsub, src8, a1, b1);
        compute_tiles(a0, b0, wm, wn, ln, quad, acc);
        __syncthreads();
        if (kt2 + 2 < 12) stage_tiles(A, Bm, bm, bn, kt2 + 2, w, rsub, src8, a0, b0);
        if (kt2 + 1 < 12) compute_tiles(a1, b1, wm, wn, ln, quad, acc);
    }

#pragma unroll
    for (int i = 0; i < 4; ++i) {
#pragma unroll
        for (int r = 0; r < 4; ++r) {
            int row_g = bm * 128 + wm * 64 + i * 16 + quad * 4 + r;
            if (row_g >= M_TOT) continue;
#pragma unroll
            for (int j = 0; j < 4; ++j) {
                int col_g = bn * 128 + wn * 64 + j * 16 + ln;
                out[(size_t)row_g * 768 + col_g] = acc[i][j][r] + pb[col_g];
            }
        }
    }
}

extern "C" void kernel_launch(void* const* d_in, const int* in_sizes, int n_in,
                              void* d_out, int out_size, void* d_ws, size_t ws_size,
                              hipStream_t stream) {
    const float* x     = (const float*)d_in[0];
    const float* qkvw  = (const float*)d_in[1];
    const float* qb    = (const float*)d_in[2];
    const float* vb    = (const float*)d_in[3];
    const float* rpb   = (const float*)d_in[4];
    const float* projw = (const float*)d_in[5];
    const float* pb    = (const float*)d_in[6];
    const int*   ridx  = (const int*)d_in[7];
    float* out = (float*)d_out;

    char* ws = (char*)d_ws;
    size_t off = 0;
    auto alloc = [&](size_t bytes) -> void* {
        void* p = ws + off;
        off = (off + bytes + 255) & ~(size_t)255;
        return p;
    };
    unsigned short* x_bf     = (unsigned short*)alloc((size_t)M_TOT * DIM_ * 2);
    unsigned short* qkvw_bf  = (unsigned short*)alloc((size_t)3 * DIM_ * DIM_ * 2);
    unsigned short* projw_bf = (unsigned short*)alloc((size_t)DIM_ * DIM_ * 2);
    float*          bias_h   = (float*)alloc((size_t)H_ * N_ * N_ * 4);
    unsigned short* q_ws     = (unsigned short*)alloc((size_t)B_ * H_ * N_ * HD_ * 2);
    unsigned short* k_ws     = (unsigned short*)alloc((size_t)B_ * H_ * N_ * HD_ * 2);
    unsigned short* v_ws     = (unsigned short*)alloc((size_t)B_ * H_ * HD_ * 224 * 2);
    unsigned short* att_ws   = (unsigned short*)alloc((size_t)(M_TOT + 64) * DIM_ * 2); // +64 rows OOB-read pad
    (void)ws_size; (void)in_sizes; (void)n_in; (void)out_size;

    k_prep<<<1200, 256, 0, stream>>>(x, qkvw, projw, rpb, ridx,
                                     x_bf, qkvw_bf, projw_bf, bias_h, v_ws);
    k_qkv<<<1782, 256, 0, stream>>>(x_bf, qkvw_bf, qb, vb, q_ws, k_ws, v_ws);
    k_attn<<<768, 256, 0, stream>>>(q_ws, k_ws, v_ws, bias_h, att_ws);
    k_proj<<<594, 256, 0, stream>>>(att_ws, projw_bf, pb, out);
}